// Round 16
// baseline (28.569 us; speedup 1.0000x reference)
//
#include <hip/hip_runtime.h>
#include <hip/hip_bf16.h>

typedef __attribute__((ext_vector_type(8))) short bf16x8;
typedef __attribute__((ext_vector_type(4))) float f32x4;

#define NPIX 32768

// ws byte layout (fragment-order packed weights):
//   [0, 32768)      W1p bf16: elem ((kk*4+dt)*64+ln)*8+cc  (kk<8, dt<4)
//   [32768, 51200)  W2p bf16: elem ((kk*9+et)*64+ln)*8+cc  (kk<2, et<9)
//   [51200, 51456)  b1f f32 [64]  (BN-folded bias)

__device__ __forceinline__ ushort f2bf(float f) {
    __hip_bfloat16 h = __float2bfloat16(f);   // single v_cvt, RNE
    ushort u; __builtin_memcpy(&u, &h, 2);
    return u;
}

__device__ __forceinline__ bf16x8 cvt8(f32x4 a, f32x4 b) {
    bf16x8 r;
    r[0] = (short)f2bf(a.x); r[1] = (short)f2bf(a.y);
    r[2] = (short)f2bf(a.z); r[3] = (short)f2bf(a.w);
    r[4] = (short)f2bf(b.x); r[5] = (short)f2bf(b.y);
    r[6] = (short)f2bf(b.z); r[7] = (short)f2bf(b.w);
    return r;
}

__global__ __launch_bounds__(256) void fold_kernel(
        const float* __restrict__ W1, const float* __restrict__ b1,
        const float* __restrict__ gamma, const float* __restrict__ beta,
        const float* __restrict__ mean, const float* __restrict__ var,
        const float* __restrict__ W2, void* __restrict__ ws) {
    ushort* w1p = (ushort*)ws;
    ushort* w2p = (ushort*)ws + 16384;
    float*  b1f = (float*)((char*)ws + 51200);
    int tid = blockIdx.x * 256 + threadIdx.x;
    if (tid < 16384) {
        int cc = tid & 7, ln = (tid >> 3) & 63, dt = (tid >> 9) & 3, kk = tid >> 11;
        int d = dt * 16 + (ln & 15);
        int c = kk * 32 + ((ln >> 4) & 3) * 8 + cc;
        float scale = gamma[d] * rsqrtf(var[d] + 1e-3f);
        w1p[tid] = f2bf(W1[c * 64 + d] * scale);
    }
    if (tid < 9216) {
        int cc = tid & 7, ln = (tid >> 3) & 63, rem = tid >> 9;  // rem<18
        int et = rem % 9, kk = rem / 9;
        int e = et * 16 + (ln & 15);
        int dcol = kk * 32 + ((ln >> 4) & 3) * 8 + cc;
        w2p[tid] = f2bf(W2[dcol * 144 + e]);
    }
    if (tid < 64) {
        float scale = gamma[tid] * rsqrtf(var[tid] + 1e-3f);
        b1f[tid] = (b1[tid] - mean[tid]) * scale + beta[tid];
    }
}

// R15 structure + x staged via global_load_lds (width 16, NO VGPR round
// trip): xs is f32 [16 rows][1024 B] per wave, LINEAR dest, swizzle done by
// PRE-SWIZZLING the per-lane global source (slot ln ^ (it&7)); GEMM1 reads
// slot (kk*8+g*2+b)^(r16&7) -> 2-way bank alias (free) and converts f32->
// bf16 in-loop (hidden under 32 MFMAs). Explicit s_waitcnt vmcnt(0) guards
// the gload_lds -> ds_read dependency (zero-barrier kernel).
// Wave-private LDS arenas (18432 B per wave):
//   phase A: xs f32 [16 rows][1024 B] @arena+0 (16 KB, linear+src-swizzled)
//   phase B: hs bf16 [16 rows][128 B] @arena+16384, swizzled (relu(h))
//   phase C: ks f32 [16][148] @arena+0 (9472 B; aliases xs -- safe: written
//            after all xs LDS reads, per-wave in-order)
// Block = 1 image row (64 px), 4 waves; 73728 B LDS -> 2 blocks/CU.
// XCD k owns image k for halo L2 locality.
__global__ __launch_bounds__(256, 2) void fused_kernel(
        const float* __restrict__ x, const void* __restrict__ ws,
        const float* __restrict__ b2, float* __restrict__ ker,
        float* __restrict__ out) {
    __shared__ __align__(16) char smem[73728];
    const int t = threadIdx.x;
    const int wv = t >> 6, ln = t & 63;
    char* arena = smem + wv * 18432;
    const int bid = (int)blockIdx.x;
    const int lb = (bid & 7) * 64 + (bid >> 3);  // XCD k <- image k
    const int p0 = lb * 64;
    const ushort* w1p = (const ushort*)ws;
    const ushort* w2p = (const ushort*)ws + 16384;
    const float*  b1f = (const float*)((const char*)ws + 51200);
    const int r16 = ln & 15, g = ln >> 4;

    // ---- stage wave's 16 x-rows via global_load_lds (f32, src-swizzled) ----
    {
        const f32x4* xg = (const f32x4*)(x + (size_t)(p0 + wv * 16) * 256);
        #pragma unroll
        for (int it = 0; it < 16; it++) {
            __builtin_amdgcn_global_load_lds(
                (const uint*)(xg + it * 64 + (ln ^ (it & 7))),
                (uint*)(arena + it * 1024), 16, 0, 0);
        }
    }
    asm volatile("s_waitcnt vmcnt(0)" ::: "memory");

    // ---- GEMM1: 16 px x 64 d; A from xs (f32 -> bf16 in-loop), B from W1p ----
    f32x4 acc[4];
    #pragma unroll
    for (int dt = 0; dt < 4; dt++) {
        float bv = b1f[dt * 16 + r16];
        acc[dt] = (f32x4){bv, bv, bv, bv};
    }
    #pragma unroll
    for (int kk = 0; kk < 8; kk++) {
        int s0 = (kk * 8 + g * 2) ^ (r16 & 7);
        int s1 = (kk * 8 + g * 2 + 1) ^ (r16 & 7);
        f32x4 a0 = *(const f32x4*)(arena + r16 * 1024 + s0 * 16);
        f32x4 a1 = *(const f32x4*)(arena + r16 * 1024 + s1 * 16);
        bf16x8 av = cvt8(a0, a1);
        #pragma unroll
        for (int dt = 0; dt < 4; dt++) {
            bf16x8 bv = *(const bf16x8*)(w1p + (((kk * 4 + dt) << 6) + ln) * 8);
            acc[dt] = __builtin_amdgcn_mfma_f32_16x16x32_bf16(av, bv, acc[dt], 0, 0, 0);
        }
    }

    // relu -> bf16 -> hs (arena+16384, local rows 0..15, swizzled)
    #pragma unroll
    for (int dt = 0; dt < 4; dt++) {
        #pragma unroll
        for (int r = 0; r < 4; r++) {
            int q = g * 4 + r;                        // local px (C/D row)
            int bcol = ((dt * 16 + r16) * 2) ^ ((q & 7) << 4);
            *(ushort*)(arena + 16384 + q * 128 + bcol) = f2bf(fmaxf(acc[dt][r], 0.f));
        }
    }

    // ---- invol window preload: latency hides under GEMM2 ----
    const int i  = lb & 63;
    const f32x4* xv4 = (const f32x4*)x;
    const int j0 = wv * 16;
    const f32x4 z4 = {0.f, 0.f, 0.f, 0.f};
    f32x4 wa[3], wb[3], wc[3], wd[3];   // cols j-1, j, j+1, j+2
    #pragma unroll
    for (int r = 0; r < 3; r++) {
        int row = i + r - 1;
        bool rv = (unsigned)row < 64u;
        const size_t rb = (size_t)(lb + r - 1) * 64;
        wa[r] = (rv && j0 > 0) ? xv4[(rb + (j0 - 1)) * 64 + ln] : z4;
        wb[r] = rv ? xv4[(rb + j0) * 64 + ln] : z4;
        wc[r] = rv ? xv4[(rb + j0 + 1) * 64 + ln] : z4;   // j0+1 <= 49 < 64
        wd[r] = rv ? xv4[(rb + j0 + 2) * 64 + ln] : z4;   // j0+2 <= 50 < 64
    }

    // ---- GEMM2: 16 px x 144 e; A from hs, B coalesced from W2p ----
    f32x4 acc2[9];
    #pragma unroll
    for (int et = 0; et < 9; et++) {
        float bv = b2[et * 16 + r16];
        acc2[et] = (f32x4){bv, bv, bv, bv};
    }
    #pragma unroll
    for (int kk = 0; kk < 2; kk++) {
        int bcA = (kk * 64 + g * 16) ^ ((r16 & 7) << 4);
        bf16x8 av = *(const bf16x8*)(arena + 16384 + r16 * 128 + bcA);
        #pragma unroll
        for (int et = 0; et < 9; et++) {
            bf16x8 bv = *(const bf16x8*)(w2p + (((kk * 9 + et) << 6) + ln) * 8);
            acc2[et] = __builtin_amdgcn_mfma_f32_16x16x32_bf16(av, bv, acc2[et], 0, 0, 0);
        }
    }

    // ---- ks: f32 transpose into wave arena (LDS only); acc2 dies here ----
    float* ksf = (float*)arena;                       // [16][148]
    #pragma unroll
    for (int et = 0; et < 9; et++) {
        #pragma unroll
        for (int r = 0; r < 4; r++) {
            int q = g * 4 + r;
            ksf[q * 148 + et * 16 + r16] = acc2[et][r];
        }
    }

    // ---- involution: 4-column shift window, prefetch depth 2 ----
    const int s4 = (ln & 3) * 4;
    #pragma unroll 4
    for (int pp = 0; pp < 16; pp++) {
        const int j = j0 + pp;
        const float* kp = ksf + pp * 148 + s4;
        f32x4 o = {0.f, 0.f, 0.f, 0.f};
        #pragma unroll
        for (int r = 0; r < 3; r++) {
            o += (*(const f32x4*)(kp + (r * 3 + 0) * 16)) * wa[r];
            o += (*(const f32x4*)(kp + (r * 3 + 1) * 16)) * wb[r];
            o += (*(const f32x4*)(kp + (r * 3 + 2) * 16)) * wc[r];
        }
        __builtin_nontemporal_store(o, &((f32x4*)out)[(size_t)(p0 + j) * 64 + ln]);
        #pragma unroll
        for (int r = 0; r < 3; r++) { wa[r] = wb[r]; wb[r] = wc[r]; wc[r] = wd[r]; }
        if (pp < 14) {
            const int jn = j + 3;                      // consumed at pp+2
            const bool cv = jn < 64;
            #pragma unroll
            for (int r = 0; r < 3; r++) {
                int row = i + r - 1;
                bool rv = (unsigned)row < 64u;
                wd[r] = (rv && cv)
                    ? xv4[((size_t)(lb + r - 1) * 64 + jn) * 64 + ln] : z4;
            }
        }
    }

    // ---- coalesced ker epilogue: ksf -> 9 x 1KB contiguous NT stores ----
    {
        float* kerW = ker + (size_t)(p0 + wv * 16) * 144;   // wave's 2304 floats
        #pragma unroll
        for (int m = 0; m < 9; m++) {
            int fidx = m * 64 + ln;          // f32x4 index within wave region
            int row  = fidx / 36;            // px row 0..15
            int col4 = fidx - row * 36;      // f32x4 within row (144/4=36)
            f32x4 v = *(const f32x4*)(ksf + row * 148 + col4 * 4);
            __builtin_nontemporal_store(v, (f32x4*)(kerW + fidx * 4));
        }
    }
}

extern "C" void kernel_launch(void* const* d_in, const int* in_sizes, int n_in,
                              void* d_out, int out_size, void* d_ws, size_t ws_size,
                              hipStream_t stream) {
    const float* x     = (const float*)d_in[0];
    const float* W1    = (const float*)d_in[1];
    const float* b1    = (const float*)d_in[2];
    const float* gamma = (const float*)d_in[3];
    const float* beta  = (const float*)d_in[4];
    const float* mmean = (const float*)d_in[5];
    const float* mvar  = (const float*)d_in[6];
    const float* W2    = (const float*)d_in[7];
    const float* b2    = (const float*)d_in[8];

    float* out_main = (float*)d_out;                 // (B,H,W,C)   = 8388608 f32
    float* out_ker  = (float*)d_out + 8388608;       // (B,H,W,144) = 4718592 f32

    fold_kernel<<<64, 256, 0, stream>>>(W1, b1, gamma, beta, mmean, mvar, W2, d_ws);
    fused_kernel<<<NPIX / 64, 256, 0, stream>>>(x, d_ws, b2, out_ker, out_main);
}